// Round 1
// 219.184 us; speedup vs baseline: 1.1122x; 1.1122x over previous
//
#include <hip/hip_runtime.h>

// PlatonicConv: linear attention with tetrahedral-group RoPE.
// N=32768 nodes, C=E=384, G=12 groups, H=1, D=32, P=16, 64 graphs (batch sorted).
// I/O fp32; internal bf16 MFMA with fp32 accumulate.
//
// Round 8 (from rocprof: kv_k 50.7us with MfmaUtil 0 / VALU 17% / HBM 10% ->
// latency+LDS-serialization bound, 27MB atomic write amplification):
//  - kv_k replaced by kv_mfma: one block per (graph, group), 32x32xK GEMM via
//    v_mfma_f32_32x32x16_bf16 over the graph's nodes. No atomics, no memset.
//  - binary search on sorted batch for segment bounds; tail masked in-fragment.
//  - V chunk staged via global_load_lds w16; XCD swizzle groups a graph's 12
//    blocks on one XCD (grp 2k/2k+1 share 128B lines of V).
// Pipeline (5 dispatches): prep, gemm_qv, kv_mfma, attn_k, gemm_out.

#define N_NODES 32768
#define K_DIM   384
#define P_PAIR  16
#define NUM_GRAPHS 64

typedef unsigned short u16;
typedef __bf16 bf16x8 __attribute__((ext_vector_type(8)));
typedef float  f32x4  __attribute__((ext_vector_type(4)));
typedef float  f32x16 __attribute__((ext_vector_type(16)));
typedef __attribute__((address_space(3))) void       lds_void;
typedef const __attribute__((address_space(1))) void gbl_void;

__device__ __forceinline__ u16 f2bf(float f) {
    unsigned int i = __float_as_uint(f);
    unsigned int r = i + 0x7FFFu + ((i >> 16) & 1u);   // RNE
    return (u16)(r >> 16);
}
__device__ __forceinline__ float bf2f(u16 u) {
    union { unsigned int i; float f; } x;
    x.i = ((unsigned int)u) << 16;
    return x.f;
}

// ---------------------------------------------------------------------------
// prep: xb = bf16(x) (vectorized x8); WqvT[n][k]=[Wq|Wv][k][n]; WoT[n][k]=Wo[k][n]
__global__ void prep(const float* __restrict__ x,
                     const float* __restrict__ Wq, const float* __restrict__ Wv,
                     const float* __restrict__ Wo,
                     u16* __restrict__ xb, u16* __restrict__ WqvT,
                     u16* __restrict__ WoT) {
    int b = blockIdx.x;
    if (b < 6144) {                              // 6144*256*8 = 12,582,912 = N*384
        int i = (b * 256 + threadIdx.x) * 8;
        float4 a0 = *reinterpret_cast<const float4*>(x + i);
        float4 a1 = *reinterpret_cast<const float4*>(x + i + 4);
        union { u16 u[8]; float4 v; } pk;
        pk.u[0] = f2bf(a0.x); pk.u[1] = f2bf(a0.y);
        pk.u[2] = f2bf(a0.z); pk.u[3] = f2bf(a0.w);
        pk.u[4] = f2bf(a1.x); pk.u[5] = f2bf(a1.y);
        pk.u[6] = f2bf(a1.z); pk.u[7] = f2bf(a1.w);
        *reinterpret_cast<float4*>(xb + i) = pk.v;
    } else {
        int idx = (b - 6144) * 256 + threadIdx.x;    // < 442,368 (grid exact)
        if (idx < 294912) {
            int n = idx / 384, k = idx % 384;
            WqvT[idx] = f2bf(n < 384 ? Wq[k * 384 + n] : Wv[k * 384 + (n - 384)]);
        } else {
            int j = idx - 294912;
            int n = j / 384, k = j % 384;
            WoT[j] = f2bf(Wo[k * 384 + n]);
        }
    }
}

// ---------------------------------------------------------------------------
// Shared GEMM core: 128x128 tile, BK=32, glds width-16 staging into unpadded
// 128x32 bf16 LDS tiles (A at T[0:4096], B at T[4096:8192] u16), 4 waves 2x2,
// 4x4 16x16x32 MFMA. Staging: 16 segments of 1024B; lane l of segment s covers
// row s*16 + l/4, cols (l&3)*8 -> LDS offset exactly lane*16 B (glds order).
#define GEMM_CORE(A_PTR, B_PTR)                                                  \
    __shared__ __align__(1024) u16 T[8192];                                      \
    const int tid = threadIdx.x;                                                 \
    const int w = tid >> 6, lane = tid & 63;                                     \
    const int wr = (w >> 1) << 6, wc = (w & 1) << 6;                             \
    const int lm = lane & 15, q = lane >> 4;                                     \
    const int srow = lane >> 2, sc8 = (lane & 3) << 3;                           \
    f32x4 acc[4][4];                                                             \
    _Pragma("unroll") for (int i = 0; i < 4; i++)                                \
    _Pragma("unroll") for (int j = 0; j < 4; j++)                                \
    _Pragma("unroll") for (int r = 0; r < 4; r++) acc[i][j][r] = 0.0f;           \
    for (int k0 = 0; k0 < K_DIM; k0 += 32) {                                     \
        __syncthreads();                                                         \
        _Pragma("unroll")                                                        \
        for (int s = w; s < 16; s += 4) {                                        \
            int row = ((s & 7) << 4) + srow;                                     \
            const u16* gp = ((s >> 3) ? (B_PTR) + (size_t)(n0 + row) * K_DIM     \
                                      : (A_PTR) + (size_t)(m0 + row) * K_DIM)    \
                            + k0 + sc8;                                          \
            __builtin_amdgcn_global_load_lds((gbl_void*)gp,                      \
                                             (lds_void*)&T[s << 9], 16, 0, 0);   \
        }                                                                        \
        __syncthreads();                                                         \
        bf16x8 af[4], bfr[4];                                                    \
        _Pragma("unroll") for (int i = 0; i < 4; i++) {                          \
            af[i]  = *reinterpret_cast<const bf16x8*>(&T[(wr + i * 16 + lm) * 32 + q * 8]);          \
            bfr[i] = *reinterpret_cast<const bf16x8*>(&T[4096 + (wc + i * 16 + lm) * 32 + q * 8]);   \
        }                                                                        \
        _Pragma("unroll") for (int i = 0; i < 4; i++)                            \
        _Pragma("unroll") for (int j = 0; j < 4; j++)                            \
            acc[i][j] = __builtin_amdgcn_mfma_f32_16x16x32_bf16(af[i], bfr[j], acc[i][j], 0, 0, 0);  \
    }

// ---------------------------------------------------------------------------
// [Q|V] = xb @ [Wq|Wv]^T + [bq|bv].  Swizzle: XCD owns 32 row-tiles, bx fastest.
__global__ __launch_bounds__(256) void gemm_qv(
    const u16* __restrict__ A, const u16* __restrict__ Bt,
    const float* __restrict__ bq, const float* __restrict__ bv,
    u16* __restrict__ Qw, u16* __restrict__ Vd) {
    const int b = blockIdx.x;                 // 1536 blocks
    const int xcd = b & 7, jj = b >> 3;       // jj 0..191
    const int by = xcd * 32 + jj / 6, bx = jj % 6;
    const int m0 = by << 7, n0 = bx << 7;
    GEMM_CORE(A, Bt)
    // C/D layout: col = lane&15, row = (lane>>4)*4 + r  [HW-confirmed round-4 probe]
    u16* Cq = (n0 < 384) ? Qw : Vd;
    const float* bias = (n0 < 384) ? bq : bv;
    const int coff = (n0 < 384) ? 0 : 384;
#pragma unroll
    for (int j = 0; j < 4; j++) {
        int gc = n0 + wc + j * 16 + lm - coff;
        float bs = bias[gc];
#pragma unroll
        for (int i = 0; i < 4; i++) {
            int gr = m0 + wr + i * 16 + q * 4;
#pragma unroll
            for (int r = 0; r < 4; r++)
                Cq[(size_t)(gr + r) * 384 + gc] = f2bf(acc[i][j][r] + bs);
        }
    }
}

// ---------------------------------------------------------------------------
// out = O @ Wo^T + bo (fp32 out).  O = attn output, in-place over Qw.
__global__ __launch_bounds__(256) void gemm_out(
    const u16* __restrict__ A, const u16* __restrict__ Bt,
    const float* __restrict__ bias, float* __restrict__ Cmat) {
    const int b = blockIdx.x;                 // 768 blocks
    const int xcd = b & 7, jj = b >> 3;       // jj 0..95
    const int by = xcd * 32 + jj / 3, bx = jj % 3;
    const int m0 = by << 7, n0 = bx << 7;
    GEMM_CORE(A, Bt)
#pragma unroll
    for (int j = 0; j < 4; j++) {
        int gc = n0 + wc + j * 16 + lm;
        float bs = bias[gc];
#pragma unroll
        for (int i = 0; i < 4; i++) {
            int gr = m0 + wr + i * 16 + q * 4;
#pragma unroll
            for (int r = 0; r < 4; r++)
                Cmat[(size_t)(gr + r) * 384 + gc] = acc[i][j][r] + bs;
        }
    }
}

// ---------------------------------------------------------------------------
// kv_mfma: KV[g][grp][d][e] = (1/512) sum_{n in graph g} k[n][grp][d] v[n][grp][e]
// One block per (g, grp): 768 blocks x 256 threads (4 waves).  Each wave eats
// 16 nodes per chunk via v_mfma_f32_32x32x16_bf16 (A = k^T 32x16, B = v 16x32).
// k = rope(ones): d=2p -> cos-sin, d=2p+1 -> sin+cos.  Segment bounds by
// binary search on sorted batch; tail nodes masked to 0 in the fragments.
// No atomics: block owns its KV[g][grp] 32x32 tile exclusively.
__global__ __launch_bounds__(256) void kv_mfma(
    const u16* __restrict__ V, const float* __restrict__ pos,
    const int* __restrict__ batch, const float* __restrict__ freqs,
    float* __restrict__ KV) {
    const int bid = blockIdx.x;               // 768 = 64 graphs * 12 groups
    // XCD swizzle: all 12 grp-blocks of a graph on one XCD (V-line sharing).
    const int xcd = bid & 7, jj = bid >> 3;   // jj 0..95
    const int g = (xcd << 3) + jj / 12, grp = jj % 12;

    const int tid = threadIdx.x;
    const int w = tid >> 6, lane = tid & 63;
    const int hi = lane >> 5, de = lane & 31; // A-row d == B-col e == de
    const int p = de >> 1, sgn = de & 1;

    const float f0 = freqs[(grp * P_PAIR + p) * 3 + 0];
    const float f1 = freqs[(grp * P_PAIR + p) * 3 + 1];
    const float f2 = freqs[(grp * P_PAIR + p) * 3 + 2];

    // segment bounds (uniform across block; redundant per-thread, L2-cached)
    int s0 = 0, s1 = N_NODES;
    while (s0 < s1) { int m = (s0 + s1) >> 1; if (batch[m] < g) s0 = m + 1; else s1 = m; }
    const int start = s0;
    int e0 = start, e1 = N_NODES;
    while (e0 < e1) { int m = (e0 + e1) >> 1; if (batch[m] < g + 1) e0 = m + 1; else e1 = m; }
    const int end = e0;

    __shared__ __align__(1024) u16 vbuf[2048];   // 64 nodes x 32 e (bf16), 4KB
    __shared__ float posb[192];                  // 64 nodes x 3
    __shared__ __align__(16) float red[4096];    // 4 waves x 32x32 partials

    f32x16 acc;
#pragma unroll
    for (int r = 0; r < 16; r++) acc[r] = 0.0f;

    const int nl0 = w * 16 + hi * 8;             // this half-wave's first local node

    for (int c = start; c < end; c += 64) {
        __syncthreads();                         // prior chunk's readers done
        if (tid < 192) {                         // stage pos[c .. c+64)
            int i = c * 3 + tid;
            posb[tid] = (i < 3 * N_NODES) ? pos[i] : 0.0f;
        }
        {                                        // stage V slice: 64 rows x 64B
            int r = tid >> 2;
            int nn = c + r;
            const u16* gp = V + (size_t)nn * K_DIM + (grp << 5) + ((tid & 3) << 3);
            if (nn < N_NODES)
                __builtin_amdgcn_global_load_lds((gbl_void*)gp,
                                                 (lds_void*)&vbuf[w << 9], 16, 0, 0);
        }
        __syncthreads();                         // drains vmcnt (glds) too

        union { bf16x8 v; u16 u[8]; } A, B;
#pragma unroll
        for (int j = 0; j < 8; j++) {
            int nl = nl0 + j;                    // local node 0..63
            int n = c + nl;
            float ph = posb[nl * 3 + 0] * f0 + posb[nl * 3 + 1] * f1
                     + posb[nl * 3 + 2] * f2;
            float sn, cs;
            __sincosf(ph, &sn, &cs);
            float kd = sgn ? (sn + cs) : (cs - sn);
            bool valid = n < end;
            A.u[j] = valid ? f2bf(kd) : (u16)0;
            B.u[j] = valid ? vbuf[(nl << 5) + de] : (u16)0;
        }
        acc = __builtin_amdgcn_mfma_f32_32x32x16_bf16(A.v, B.v, acc, 0, 0, 0);
    }

    // reduce 4 wave-partials through LDS; C/D map: col=lane&31,
    // row=(reg&3)+8*(reg>>2)+4*(lane>>5)  [guide m74/m101]
#pragma unroll
    for (int r = 0; r < 16; r++) {
        int d = (r & 3) + ((r >> 2) << 3) + (hi << 2);
        red[(w << 10) + (d << 5) + de] = acc[r];
    }
    __syncthreads();
    {
        int i4 = tid << 2;
        f32x4 a0 = *reinterpret_cast<const f32x4*>(&red[i4]);
        f32x4 a1 = *reinterpret_cast<const f32x4*>(&red[1024 + i4]);
        f32x4 a2 = *reinterpret_cast<const f32x4*>(&red[2048 + i4]);
        f32x4 a3 = *reinterpret_cast<const f32x4*>(&red[3072 + i4]);
        f32x4 s = (a0 + a1 + a2 + a3) * (1.0f / 512.0f);
        *reinterpret_cast<f32x4*>(&KV[((size_t)(g * 12 + grp) << 10) + i4]) = s;
    }
}

// ---------------------------------------------------------------------------
// O[n][grp*32+e] = sum_d qrot[n][grp][d] * KV[batch[n]][grp][d][e].  In-place over Qw.
__global__ __launch_bounds__(384) void attn_k(
    u16* __restrict__ Qw, const float* __restrict__ pos,
    const int* __restrict__ batch, const float* __restrict__ freqs,
    const float* __restrict__ KV) {
    const int nb = blockIdx.x << 6;
    const int t = threadIdx.x;
    const int grp = t >> 5, ec = t & 31;
    const int p = ec >> 1, sgn = ec & 1;
    const float f0 = freqs[(grp * P_PAIR + p) * 3 + 0];
    const float f1 = freqs[(grp * P_PAIR + p) * 3 + 1];
    const float f2 = freqs[(grp * P_PAIR + p) * 3 + 2];

    __shared__ float qbuf[8][384];
    __shared__ int gbuf[8];
    float kv[32];
    int gcur = -1;
    const int cq = t & ~1;

    for (int base = nb; base < nb + 64; base += 8) {
        __syncthreads();
        if (t < 8) gbuf[t] = batch[base + t];
#pragma unroll
        for (int i = 0; i < 8; i++) {
            int n = base + i;
            float qa = bf2f(Qw[(size_t)n * 384 + cq]);
            float qb = bf2f(Qw[(size_t)n * 384 + cq + 1]);
            float ph = pos[n * 3 + 0] * f0 + pos[n * 3 + 1] * f1 + pos[n * 3 + 2] * f2;
            float sn, cs;
            __sincosf(ph, &sn, &cs);
            qbuf[i][t] = sgn ? (qa * sn + qb * cs) : (qa * cs - qb * sn);
        }
        __syncthreads();
#pragma unroll
        for (int i = 0; i < 8; i++) {
            int g = gbuf[i];                            // block-uniform
            if (g != gcur) {
                gcur = g;
                const float* src = KV + ((g * 12 + grp) << 10) + ec;
#pragma unroll
                for (int d = 0; d < 32; d++) kv[d] = src[d << 5];
            }
            const float* qr = &qbuf[i][grp << 5];
            float o = 0.0f;
#pragma unroll
            for (int d = 0; d < 32; d++) o = fmaf(qr[d], kv[d], o);
            Qw[(size_t)(base + i) * 384 + t] = f2bf(o);
        }
    }
}

// ---------------------------------------------------------------------------
extern "C" void kernel_launch(void* const* d_in, const int* in_sizes, int n_in,
                              void* d_out, int out_size, void* d_ws, size_t ws_size,
                              hipStream_t stream) {
    const float* x     = (const float*)d_in[0];
    const float* pos   = (const float*)d_in[1];
    const int*   batch = (const int*)d_in[2];
    const float* Wq    = (const float*)d_in[3];
    const float* bq    = (const float*)d_in[4];
    const float* Wv    = (const float*)d_in[5];
    const float* bv    = (const float*)d_in[6];
    const float* Wo    = (const float*)d_in[7];
    const float* bo    = (const float*)d_in[8];
    const float* fr    = (const float*)d_in[9];
    float* out = (float*)d_out;

    char* ws = (char*)d_ws;                   // total use ~29.2 MB
    float* KV   = (float*)(ws);               //  3,145,728 B
    u16*   WqvT = (u16*)(ws + 3145728);       //    589,824 B
    u16*   WoT  = (u16*)(ws + 3735552);       //    294,912 B
    u16*   Qw   = (u16*)(ws + 4030464);       // 25,165,824 B (Q, then O in-place)
    // d_out (50.3 MB fp32) doubles as scratch until gemm_out overwrites it:
    u16*   Vd   = (u16*)d_out;                // [0, 25.2 MB): V bf16
    u16*   xb   = (u16*)d_out + N_NODES * 384;// [25.2, 50.3 MB): x as bf16

    prep<<<dim3(7872), dim3(256), 0, stream>>>(x, Wq, Wv, Wo, xb, WqvT, WoT);
    gemm_qv<<<dim3(1536), dim3(256), 0, stream>>>(xb, WqvT, bq, bv, Qw, Vd);
    kv_mfma<<<dim3(768), dim3(256), 0, stream>>>(Vd, pos, batch, fr, KV);
    attn_k<<<dim3(512), dim3(384), 0, stream>>>(Qw, pos, batch, fr, KV);
    gemm_out<<<dim3(768), dim3(256), 0, stream>>>(Qw, WoT, bo, out);
}

// Round 3
// 202.853 us; speedup vs baseline: 1.2017x; 1.0805x over previous
//
#include <hip/hip_runtime.h>

// PlatonicConv: linear attention with tetrahedral-group RoPE.
// N=32768 nodes, C=E=384, G=12 groups, H=1, D=32, P=16, 64 graphs (batch sorted).
// I/O fp32; internal bf16 MFMA with fp32 accumulate.
//
// Round 10 (bisection after round-9 fusion failed at absmax 0.099):
//  - kv_mfma and gemm_out reverted to round-8 verified forms (fp32 KV flat
//    [d][e]; plain GEMM_CORE gemm_out).
//  - ONE new kernel: attn_mfma replaces scalar attn_k. Per (128-node chunk,
//    group) block: rope(Q) in-lane -> masked per-graph 32x32x16 MFMAs against
//    KV (fp32 -> bf16 fragments in-register) -> O via LDS -> coalesced
//    in-place bf16 write to Qw. Isolates the O-step math.
// Pipeline (5 dispatches): prep, gemm_qv, kv_mfma, attn_mfma, gemm_out.

#define N_NODES 32768
#define K_DIM   384
#define P_PAIR  16
#define NUM_GRAPHS 64

typedef unsigned short u16;
typedef __bf16 bf16x8 __attribute__((ext_vector_type(8)));
typedef float  f32x4  __attribute__((ext_vector_type(4)));
typedef float  f32x16 __attribute__((ext_vector_type(16)));
typedef __attribute__((address_space(3))) void       lds_void;
typedef const __attribute__((address_space(1))) void gbl_void;

__device__ __forceinline__ u16 f2bf(float f) {
    unsigned int i = __float_as_uint(f);
    unsigned int r = i + 0x7FFFu + ((i >> 16) & 1u);   // RNE
    return (u16)(r >> 16);
}
__device__ __forceinline__ float bf2f(u16 u) {
    union { unsigned int i; float f; } x;
    x.i = ((unsigned int)u) << 16;
    return x.f;
}

// ---------------------------------------------------------------------------
// prep: xb = bf16(x) (vectorized x8); WqvT[n][k]=[Wq|Wv][k][n]; WoT[n][k]=Wo[k][n]
__global__ void prep(const float* __restrict__ x,
                     const float* __restrict__ Wq, const float* __restrict__ Wv,
                     const float* __restrict__ Wo,
                     u16* __restrict__ xb, u16* __restrict__ WqvT,
                     u16* __restrict__ WoT) {
    int b = blockIdx.x;
    if (b < 6144) {                              // 6144*256*8 = 12,582,912 = N*384
        int i = (b * 256 + threadIdx.x) * 8;
        float4 a0 = *reinterpret_cast<const float4*>(x + i);
        float4 a1 = *reinterpret_cast<const float4*>(x + i + 4);
        union { u16 u[8]; float4 v; } pk;
        pk.u[0] = f2bf(a0.x); pk.u[1] = f2bf(a0.y);
        pk.u[2] = f2bf(a0.z); pk.u[3] = f2bf(a0.w);
        pk.u[4] = f2bf(a1.x); pk.u[5] = f2bf(a1.y);
        pk.u[6] = f2bf(a1.z); pk.u[7] = f2bf(a1.w);
        *reinterpret_cast<float4*>(xb + i) = pk.v;
    } else {
        int idx = (b - 6144) * 256 + threadIdx.x;    // < 442,368 (grid exact)
        if (idx < 294912) {
            int n = idx / 384, k = idx % 384;
            WqvT[idx] = f2bf(n < 384 ? Wq[k * 384 + n] : Wv[k * 384 + (n - 384)]);
        } else {
            int j = idx - 294912;
            int n = j / 384, k = j % 384;
            WoT[j] = f2bf(Wo[k * 384 + n]);
        }
    }
}

// ---------------------------------------------------------------------------
// Shared GEMM core: 128x128 tile, BK=32, glds width-16 staging into unpadded
// 128x32 bf16 LDS tiles (A at T[0:4096], B at T[4096:8192] u16), 4 waves 2x2,
// 4x4 16x16x32 MFMA.
#define GEMM_CORE(A_PTR, B_PTR)                                                  \
    __shared__ __align__(1024) u16 T[8192];                                      \
    const int tid = threadIdx.x;                                                 \
    const int w = tid >> 6, lane = tid & 63;                                     \
    const int wr = (w >> 1) << 6, wc = (w & 1) << 6;                             \
    const int lm = lane & 15, q = lane >> 4;                                     \
    const int srow = lane >> 2, sc8 = (lane & 3) << 3;                           \
    f32x4 acc[4][4];                                                             \
    _Pragma("unroll") for (int i = 0; i < 4; i++)                                \
    _Pragma("unroll") for (int j = 0; j < 4; j++)                                \
    _Pragma("unroll") for (int r = 0; r < 4; r++) acc[i][j][r] = 0.0f;           \
    for (int k0 = 0; k0 < K_DIM; k0 += 32) {                                     \
        __syncthreads();                                                         \
        _Pragma("unroll")                                                        \
        for (int s = w; s < 16; s += 4) {                                        \
            int row = ((s & 7) << 4) + srow;                                     \
            const u16* gp = ((s >> 3) ? (B_PTR) + (size_t)(n0 + row) * K_DIM     \
                                      : (A_PTR) + (size_t)(m0 + row) * K_DIM)    \
                            + k0 + sc8;                                          \
            __builtin_amdgcn_global_load_lds((gbl_void*)gp,                      \
                                             (lds_void*)&T[s << 9], 16, 0, 0);   \
        }                                                                        \
        __syncthreads();                                                         \
        bf16x8 af[4], bfr[4];                                                    \
        _Pragma("unroll") for (int i = 0; i < 4; i++) {                          \
            af[i]  = *reinterpret_cast<const bf16x8*>(&T[(wr + i * 16 + lm) * 32 + q * 8]);          \
            bfr[i] = *reinterpret_cast<const bf16x8*>(&T[4096 + (wc + i * 16 + lm) * 32 + q * 8]);   \
        }                                                                        \
        _Pragma("unroll") for (int i = 0; i < 4; i++)                            \
        _Pragma("unroll") for (int j = 0; j < 4; j++)                            \
            acc[i][j] = __builtin_amdgcn_mfma_f32_16x16x32_bf16(af[i], bfr[j], acc[i][j], 0, 0, 0);  \
    }

// ---------------------------------------------------------------------------
// [Q|V] = xb @ [Wq|Wv]^T + [bq|bv].  Swizzle: XCD owns 32 row-tiles, bx fastest.
__global__ __launch_bounds__(256) void gemm_qv(
    const u16* __restrict__ A, const u16* __restrict__ Bt,
    const float* __restrict__ bq, const float* __restrict__ bv,
    u16* __restrict__ Qw, u16* __restrict__ Vd) {
    const int b = blockIdx.x;                 // 1536 blocks
    const int xcd = b & 7, jj = b >> 3;       // jj 0..191
    const int by = xcd * 32 + jj / 6, bx = jj % 6;
    const int m0 = by << 7, n0 = bx << 7;
    GEMM_CORE(A, Bt)
    // C/D layout: col = lane&15, row = (lane>>4)*4 + r  [HW-confirmed]
    u16* Cq = (n0 < 384) ? Qw : Vd;
    const float* bias = (n0 < 384) ? bq : bv;
    const int coff = (n0 < 384) ? 0 : 384;
#pragma unroll
    for (int j = 0; j < 4; j++) {
        int gc = n0 + wc + j * 16 + lm - coff;
        float bs = bias[gc];
#pragma unroll
        for (int i = 0; i < 4; i++) {
            int gr = m0 + wr + i * 16 + q * 4;
#pragma unroll
            for (int r = 0; r < 4; r++)
                Cq[(size_t)(gr + r) * 384 + gc] = f2bf(acc[i][j][r] + bs);
        }
    }
}

// ---------------------------------------------------------------------------
// out = O @ Wo^T + bo (fp32 out).  O = attn output, in-place over Qw.
__global__ __launch_bounds__(256) void gemm_out(
    const u16* __restrict__ A, const u16* __restrict__ Bt,
    const float* __restrict__ bias, float* __restrict__ Cmat) {
    const int b = blockIdx.x;                 // 768 blocks
    const int xcd = b & 7, jj = b >> 3;       // jj 0..95
    const int by = xcd * 32 + jj / 3, bx = jj % 3;
    const int m0 = by << 7, n0 = bx << 7;
    GEMM_CORE(A, Bt)
#pragma unroll
    for (int j = 0; j < 4; j++) {
        int gc = n0 + wc + j * 16 + lm;
        float bs = bias[gc];
#pragma unroll
        for (int i = 0; i < 4; i++) {
            int gr = m0 + wr + i * 16 + q * 4;
#pragma unroll
            for (int r = 0; r < 4; r++)
                Cmat[(size_t)(gr + r) * 384 + gc] = acc[i][j][r] + bs;
        }
    }
}

// ---------------------------------------------------------------------------
// kv_mfma: KV[g][grp][d][e] = (1/512) sum_{n in graph g} k[n][grp][d] v[n][grp][e]
// One block per (g, grp): 768 blocks x 256 threads (4 waves), 32x32xK MFMA
// over the graph's nodes.  k = rope(ones).  fp32 flat [d][e] output. VERIFIED.
__global__ __launch_bounds__(256) void kv_mfma(
    const u16* __restrict__ V, const float* __restrict__ pos,
    const int* __restrict__ batch, const float* __restrict__ freqs,
    float* __restrict__ KV) {
    const int bid = blockIdx.x;               // 768 = 64 graphs * 12 groups
    const int xcd = bid & 7, jj = bid >> 3;   // jj 0..95
    const int g = (xcd << 3) + jj / 12, grp = jj % 12;

    const int tid = threadIdx.x;
    const int w = tid >> 6, lane = tid & 63;
    const int hi = lane >> 5, de = lane & 31; // A-row d == B-col e == de
    const int p = de >> 1, sgn = de & 1;

    const float f0 = freqs[(grp * P_PAIR + p) * 3 + 0];
    const float f1 = freqs[(grp * P_PAIR + p) * 3 + 1];
    const float f2 = freqs[(grp * P_PAIR + p) * 3 + 2];

    // segment bounds (uniform across block)
    int s0 = 0, s1 = N_NODES;
    while (s0 < s1) { int m = (s0 + s1) >> 1; if (batch[m] < g) s0 = m + 1; else s1 = m; }
    const int start = s0;
    int e0 = start, e1 = N_NODES;
    while (e0 < e1) { int m = (e0 + e1) >> 1; if (batch[m] < g + 1) e0 = m + 1; else e1 = m; }
    const int end = e0;

    __shared__ __align__(1024) u16 vbuf[2048];   // 64 nodes x 32 e (bf16), 4KB
    __shared__ float posb[192];                  // 64 nodes x 3
    __shared__ __align__(16) float red[4096];    // 4 waves x 32x32 partials

    f32x16 acc;
#pragma unroll
    for (int r = 0; r < 16; r++) acc[r] = 0.0f;

    const int nl0 = w * 16 + hi * 8;             // this half-wave's first local node

    for (int c = start; c < end; c += 64) {
        __syncthreads();                         // prior chunk's readers done
        if (tid < 192) {                         // stage pos[c .. c+64)
            int i = c * 3 + tid;
            posb[tid] = (i < 3 * N_NODES) ? pos[i] : 0.0f;
        }
        {                                        // stage V slice: 64 rows x 64B
            int r = tid >> 2;
            int nn = c + r;
            const u16* gp = V + (size_t)nn * K_DIM + (grp << 5) + ((tid & 3) << 3);
            if (nn < N_NODES)
                __builtin_amdgcn_global_load_lds((gbl_void*)gp,
                                                 (lds_void*)&vbuf[w << 9], 16, 0, 0);
        }
        __syncthreads();                         // drains vmcnt (glds) too

        union { bf16x8 v; u16 u[8]; } A, B;
#pragma unroll
        for (int j = 0; j < 8; j++) {
            int nl = nl0 + j;                    // local node 0..63
            int n = c + nl;
            float ph = posb[nl * 3 + 0] * f0 + posb[nl * 3 + 1] * f1
                     + posb[nl * 3 + 2] * f2;
            float sn, cs;
            __sincosf(ph, &sn, &cs);
            float kd = sgn ? (sn + cs) : (cs - sn);
            bool valid = n < end;
            A.u[j] = valid ? f2bf(kd) : (u16)0;
            B.u[j] = valid ? vbuf[(nl << 5) + de] : (u16)0;
        }
        acc = __builtin_amdgcn_mfma_f32_32x32x16_bf16(A.v, B.v, acc, 0, 0, 0);
    }

    // reduce 4 wave-partials through LDS; C/D map: col=lane&31,
    // row=(reg&3)+8*(reg>>2)+4*(lane>>5)
#pragma unroll
    for (int r = 0; r < 16; r++) {
        int d = (r & 3) + ((r >> 2) << 3) + (hi << 2);
        red[(w << 10) + (d << 5) + de] = acc[r];
    }
    __syncthreads();
    {
        int i4 = tid << 2;
        f32x4 a0 = *reinterpret_cast<const f32x4*>(&red[i4]);
        f32x4 a1 = *reinterpret_cast<const f32x4*>(&red[1024 + i4]);
        f32x4 a2 = *reinterpret_cast<const f32x4*>(&red[2048 + i4]);
        f32x4 a3 = *reinterpret_cast<const f32x4*>(&red[3072 + i4]);
        f32x4 s = (a0 + a1 + a2 + a3) * (1.0f / 512.0f);
        *reinterpret_cast<f32x4*>(&KV[((size_t)(g * 12 + grp) << 10) + i4]) = s;
    }
}

// ---------------------------------------------------------------------------
// attn_mfma: O[n][grp*32+e] = sum_d rope(q)[n][grp][d] * KV[batch[n]][grp][d][e]
// One block per (128-node chunk, grp): 3072 blocks x 256 threads (4 waves).
// Per wave: 32 nodes; A = roped Q frag (row=de -> node, k=hi*8+j -> d) built
// in-lane; B = KV fp32 -> bf16 fragments; masked per-graph 32x32x16 MFMAs.
// O -> LDS fp32 -> coalesced bf16 write in-place over Qw.  In-place is safe:
// all Q reads retire before each thread's barrier arrival; writes post-barrier;
// blocks own disjoint (row x 32-col) regions.
__global__ __launch_bounds__(256) void attn_mfma(
    u16* __restrict__ Qw, const float* __restrict__ pos,
    const int* __restrict__ batch, const float* __restrict__ freqs,
    const float* __restrict__ KV) {
    const int bid = blockIdx.x;               // 3072 = 256 chunks * 12 groups
    const int xcd = bid & 7, jj = bid >> 3;   // jj 0..383
    const int chunk = (xcd << 5) + jj / 12, grp = jj % 12;
    const int nbase = chunk << 7;

    const int tid = threadIdx.x;
    const int w = tid >> 6, lane = tid & 63;
    const int hi = lane >> 5, de = lane & 31;

    __shared__ float sfreq[48];               // this grp: 16 pairs x 3
    __shared__ __align__(16) float red[4096]; // O tile fp32 [128][32]

    if (tid < 48) sfreq[tid] = freqs[grp * 48 + tid];

    const int node = nbase + (w << 5) + de;
    const float p0 = pos[node * 3 + 0];
    const float p1 = pos[node * 3 + 1];
    const float p2 = pos[node * 3 + 2];
    const int bnode = batch[node];
    const int g0 = batch[nbase + (w << 5)];
    const int g1 = batch[nbase + (w << 5) + 31];

    // raw Q fragment: A layout row = de (node), k = hi*8+j (d within group)
    union { bf16x8 v; u16 u[8]; } qlo, qhi, alo, ahi;
    {
        const u16* qp = Qw + (size_t)node * K_DIM + (grp << 5) + (hi << 3);
        qlo.v = *reinterpret_cast<const bf16x8*>(qp);        // d = hi*8+j
        qhi.v = *reinterpret_cast<const bf16x8*>(qp + 16);   // d = 16+hi*8+j
    }
    __syncthreads();                          // sfreq visible
#pragma unroll
    for (int z = 0; z < 4; z++) {
        const int pl = (hi << 2) + z;                        // pair for lo half
        const float* F  = &sfreq[pl * 3];
        const float* F2 = &sfreq[(8 + pl) * 3];              // pair for hi half
        float sn, cs, sn2, cs2;
        __sincosf(p0 * F[0]  + p1 * F[1]  + p2 * F[2],  &sn,  &cs);
        __sincosf(p0 * F2[0] + p1 * F2[1] + p2 * F2[2], &sn2, &cs2);
        float x1 = bf2f(qlo.u[2 * z]), x2 = bf2f(qlo.u[2 * z + 1]);
        alo.u[2 * z]     = f2bf(x1 * cs - x2 * sn);
        alo.u[2 * z + 1] = f2bf(x1 * sn + x2 * cs);
        float y1 = bf2f(qhi.u[2 * z]), y2 = bf2f(qhi.u[2 * z + 1]);
        ahi.u[2 * z]     = f2bf(y1 * cs2 - y2 * sn2);
        ahi.u[2 * z + 1] = f2bf(y1 * sn2 + y2 * cs2);
    }

    f32x16 oacc;
#pragma unroll
    for (int r = 0; r < 16; r++) oacc[r] = 0.0f;
    for (int g = g0; g <= g1; g++) {
        const bool msk = (bnode == g);
        union { bf16x8 v; u16 u[8]; } ml, mh, bl, bh;
#pragma unroll
        for (int j = 0; j < 8; j++) {
            ml.u[j] = msk ? alo.u[j] : (u16)0;
            mh.u[j] = msk ? ahi.u[j] : (u16)0;
        }
        const float* kvp = KV + (((size_t)(g * 12 + grp)) << 10) + de;
#pragma unroll
        for (int j = 0; j < 8; j++) {                        // B[k=d][col=e=de]
            bl.u[j] = f2bf(kvp[(hi * 8 + j) << 5]);
            bh.u[j] = f2bf(kvp[(16 + hi * 8 + j) << 5]);
        }
        oacc = __builtin_amdgcn_mfma_f32_32x32x16_bf16(ml.v, bl.v, oacc, 0, 0, 0);
        oacc = __builtin_amdgcn_mfma_f32_32x32x16_bf16(mh.v, bh.v, oacc, 0, 0, 0);
    }

    // C/D map: col=lane&31, row=(reg&3)+8*(reg>>2)+4*(lane>>5)
#pragma unroll
    for (int r = 0; r < 16; r++) {
        int rl = (r & 3) + ((r >> 2) << 3) + (hi << 2);
        red[((w << 5) + rl) * 32 + de] = oacc[r];
    }
    __syncthreads();
    {
        const int row = tid >> 1, half = tid & 1;
        union { u16 u[16]; float4 v[2]; } pk;
#pragma unroll
        for (int z = 0; z < 16; z++)
            pk.u[z] = f2bf(red[row * 32 + half * 16 + z]);
        float4* dst = reinterpret_cast<float4*>(
            Qw + (size_t)(nbase + row) * K_DIM + (grp << 5) + (half << 4));
        dst[0] = pk.v[0];
        dst[1] = pk.v[1];
    }
}

// ---------------------------------------------------------------------------
extern "C" void kernel_launch(void* const* d_in, const int* in_sizes, int n_in,
                              void* d_out, int out_size, void* d_ws, size_t ws_size,
                              hipStream_t stream) {
    const float* x     = (const float*)d_in[0];
    const float* pos   = (const float*)d_in[1];
    const int*   batch = (const int*)d_in[2];
    const float* Wq    = (const float*)d_in[3];
    const float* bq    = (const float*)d_in[4];
    const float* Wv    = (const float*)d_in[5];
    const float* bv    = (const float*)d_in[6];
    const float* Wo    = (const float*)d_in[7];
    const float* bo    = (const float*)d_in[8];
    const float* fr    = (const float*)d_in[9];
    float* out = (float*)d_out;

    char* ws = (char*)d_ws;                   // total use ~29.2 MB
    float* KV   = (float*)(ws);               //  3,145,728 B  [g][grp][d][e] fp32
    u16*   WqvT = (u16*)(ws + 3145728);       //    589,824 B
    u16*   WoT  = (u16*)(ws + 3735552);       //    294,912 B
    u16*   Qw   = (u16*)(ws + 4030464);       // 25,165,824 B (Q, then O in-place)
    // d_out (50.3 MB fp32) doubles as scratch until gemm_out overwrites it:
    u16*   Vd   = (u16*)d_out;                // [0, 25.2 MB): V bf16
    u16*   xb   = (u16*)d_out + N_NODES * 384;// [25.2, 50.3 MB): x as bf16

    prep<<<dim3(7872), dim3(256), 0, stream>>>(x, Wq, Wv, Wo, xb, WqvT, WoT);
    gemm_qv<<<dim3(1536), dim3(256), 0, stream>>>(xb, WqvT, bq, bv, Qw, Vd);
    kv_mfma<<<dim3(768), dim3(256), 0, stream>>>(Vd, pos, batch, fr, KV);
    attn_mfma<<<dim3(3072), dim3(256), 0, stream>>>(Qw, pos, batch, fr, KV);
    gemm_out<<<dim3(768), dim3(256), 0, stream>>>(Qw, WoT, bo, out);
}

// Round 4
// 195.233 us; speedup vs baseline: 1.2486x; 1.0390x over previous
//
#include <hip/hip_runtime.h>

// PlatonicConv: linear attention with tetrahedral-group RoPE.
// N=32768 nodes, C=E=384, G=12 groups, H=1, D=32, P=16, 64 graphs (batch sorted).
// I/O fp32; internal bf16 MFMA with fp32 accumulate.
//
// Round 11:
//  - prep's W-transpose was uncoalesced (stride-1536B per lane, latency-bound
//    tail): now LDS-tiled 32x32 transpose, coalesced both sides.
//  - GEMM_CORE: BK=32 -> BK=64 as four independent 128x32 sub-tiles
//    (A0|A1|B0|B1) -- same verified segment/fragment layouts, half the
//    barrier pairs (12 -> 6). Bit-identical accumulation order.
// Pipeline (5 dispatches): prep, gemm_qv, kv_mfma, attn_mfma, gemm_out.

#define N_NODES 32768
#define K_DIM   384
#define P_PAIR  16
#define NUM_GRAPHS 64

typedef unsigned short u16;
typedef __bf16 bf16x8 __attribute__((ext_vector_type(8)));
typedef float  f32x4  __attribute__((ext_vector_type(4)));
typedef float  f32x16 __attribute__((ext_vector_type(16)));
typedef __attribute__((address_space(3))) void       lds_void;
typedef const __attribute__((address_space(1))) void gbl_void;

__device__ __forceinline__ u16 f2bf(float f) {
    unsigned int i = __float_as_uint(f);
    unsigned int r = i + 0x7FFFu + ((i >> 16) & 1u);   // RNE
    return (u16)(r >> 16);
}
__device__ __forceinline__ float bf2f(u16 u) {
    union { unsigned int i; float f; } x;
    x.i = ((unsigned int)u) << 16;
    return x.f;
}

// ---------------------------------------------------------------------------
// prep: xb = bf16(x) (vectorized x8, blocks 0..6143); W transposes via
// LDS-tiled 32x32 (blocks 6144..6575): WqvT[n][k]=[Wq|Wv][k][n], WoT[n][k]=Wo[k][n].
__global__ void prep(const float* __restrict__ x,
                     const float* __restrict__ Wq, const float* __restrict__ Wv,
                     const float* __restrict__ Wo,
                     u16* __restrict__ xb, u16* __restrict__ WqvT,
                     u16* __restrict__ WoT) {
    int b = blockIdx.x;
    if (b < 6144) {                              // 6144*256*8 = 12,582,912 = N*384
        int i = (b * 256 + threadIdx.x) * 8;
        float4 a0 = *reinterpret_cast<const float4*>(x + i);
        float4 a1 = *reinterpret_cast<const float4*>(x + i + 4);
        union { u16 u[8]; float4 v; } pk;
        pk.u[0] = f2bf(a0.x); pk.u[1] = f2bf(a0.y);
        pk.u[2] = f2bf(a0.z); pk.u[3] = f2bf(a0.w);
        pk.u[4] = f2bf(a1.x); pk.u[5] = f2bf(a1.y);
        pk.u[6] = f2bf(a1.z); pk.u[7] = f2bf(a1.w);
        *reinterpret_cast<float4*>(xb + i) = pk.v;
        return;
    }
    // tiled transpose: 432 blocks = 3 matrices x 144 (12x12) 32x32 tiles
    __shared__ float ld[32][33];
    const int tb  = b - 6144;
    const int mat = tb / 144;                    // 0: Wq, 1: Wv, 2: Wo
    const int tl  = tb % 144;
    const int tr  = tl / 12, tc = tl % 12;       // src tile row (k), col (n)
    const float* src = (mat == 0) ? Wq : (mat == 1) ? Wv : Wo;
    u16* dst = (mat == 2) ? WoT : WqvT;
    const int n_off = (mat == 1) ? 384 : 0;

    const int t = threadIdx.x;
    const int c = t & 31, r = t >> 5;            // 8 rows per pass
#pragma unroll
    for (int i = 0; i < 4; i++) {
        int r0 = r + (i << 3);
        ld[r0][c] = src[(tr * 32 + r0) * 384 + tc * 32 + c];
    }
    __syncthreads();
    const int ck = t & 31;
#pragma unroll
    for (int i = 0; i < 4; i++) {
        int cn = r + (i << 3);
        dst[(size_t)(n_off + tc * 32 + cn) * 384 + tr * 32 + ck] = f2bf(ld[ck][cn]);
    }
}

// ---------------------------------------------------------------------------
// Shared GEMM core: 128x128 tile, BK=64 as four 128x32 sub-tiles
// [A0 | A1 | B0 | B1], each 4096 u16, staged via glds w16 in 8 segments of
// 1024B apiece (verified layout: lane l of segment s covers row ((s&7)<<4)+l/4,
// cols (l&3)*8 -> LDS offset lane*16B).  4 waves 2x2, 4x4 16x16x32 MFMA, two
// k-halves per K-step.  6 barrier pairs total.
#define GEMM_CORE(A_PTR, B_PTR)                                                  \
    __shared__ __align__(1024) u16 T[16384];                                     \
    const int tid = threadIdx.x;                                                 \
    const int w = tid >> 6, lane = tid & 63;                                     \
    const int wr = (w >> 1) << 6, wc = (w & 1) << 6;                             \
    const int lm = lane & 15, q = lane >> 4;                                     \
    const int srow = lane >> 2, sc8 = (lane & 3) << 3;                           \
    f32x4 acc[4][4];                                                             \
    _Pragma("unroll") for (int i = 0; i < 4; i++)                                \
    _Pragma("unroll") for (int j = 0; j < 4; j++)                                \
    _Pragma("unroll") for (int r = 0; r < 4; r++) acc[i][j][r] = 0.0f;           \
    for (int k0 = 0; k0 < K_DIM; k0 += 64) {                                     \
        __syncthreads();                                                         \
        _Pragma("unroll")                                                        \
        for (int s = w; s < 32; s += 4) {                                        \
            int row  = ((s & 7) << 4) + srow;                                    \
            int half = (s >> 3) & 1;                                             \
            const u16* gp = ((s >> 4) ? (B_PTR) + (size_t)(n0 + row) * K_DIM     \
                                      : (A_PTR) + (size_t)(m0 + row) * K_DIM)    \
                            + k0 + (half << 5) + sc8;                            \
            __builtin_amdgcn_global_load_lds((gbl_void*)gp,                      \
                                             (lds_void*)&T[s << 9], 16, 0, 0);   \
        }                                                                        \
        __syncthreads();                                                         \
        _Pragma("unroll")                                                        \
        for (int h = 0; h < 2; h++) {                                            \
            bf16x8 af[4], bfr[4];                                                \
            _Pragma("unroll") for (int i = 0; i < 4; i++) {                      \
                af[i]  = *reinterpret_cast<const bf16x8*>(                       \
                    &T[(h << 12) + (wr + i * 16 + lm) * 32 + q * 8]);            \
                bfr[i] = *reinterpret_cast<const bf16x8*>(                       \
                    &T[8192 + (h << 12) + (wc + i * 16 + lm) * 32 + q * 8]);     \
            }                                                                    \
            _Pragma("unroll") for (int i = 0; i < 4; i++)                        \
            _Pragma("unroll") for (int j = 0; j < 4; j++)                        \
                acc[i][j] = __builtin_amdgcn_mfma_f32_16x16x32_bf16(             \
                    af[i], bfr[j], acc[i][j], 0, 0, 0);                          \
        }                                                                        \
    }

// ---------------------------------------------------------------------------
// [Q|V] = xb @ [Wq|Wv]^T + [bq|bv].  Swizzle: XCD owns 32 row-tiles, bx fastest.
__global__ __launch_bounds__(256) void gemm_qv(
    const u16* __restrict__ A, const u16* __restrict__ Bt,
    const float* __restrict__ bq, const float* __restrict__ bv,
    u16* __restrict__ Qw, u16* __restrict__ Vd) {
    const int b = blockIdx.x;                 // 1536 blocks
    const int xcd = b & 7, jj = b >> 3;       // jj 0..191
    const int by = xcd * 32 + jj / 6, bx = jj % 6;
    const int m0 = by << 7, n0 = bx << 7;
    GEMM_CORE(A, Bt)
    // C/D layout: col = lane&15, row = (lane>>4)*4 + r  [HW-confirmed]
    u16* Cq = (n0 < 384) ? Qw : Vd;
    const float* bias = (n0 < 384) ? bq : bv;
    const int coff = (n0 < 384) ? 0 : 384;
#pragma unroll
    for (int j = 0; j < 4; j++) {
        int gc = n0 + wc + j * 16 + lm - coff;
        float bs = bias[gc];
#pragma unroll
        for (int i = 0; i < 4; i++) {
            int gr = m0 + wr + i * 16 + q * 4;
#pragma unroll
            for (int r = 0; r < 4; r++)
                Cq[(size_t)(gr + r) * 384 + gc] = f2bf(acc[i][j][r] + bs);
        }
    }
}

// ---------------------------------------------------------------------------
// out = O @ Wo^T + bo (fp32 out).  O = attn output, in-place over Qw.
__global__ __launch_bounds__(256) void gemm_out(
    const u16* __restrict__ A, const u16* __restrict__ Bt,
    const float* __restrict__ bias, float* __restrict__ Cmat) {
    const int b = blockIdx.x;                 // 768 blocks
    const int xcd = b & 7, jj = b >> 3;       // jj 0..95
    const int by = xcd * 32 + jj / 3, bx = jj % 3;
    const int m0 = by << 7, n0 = bx << 7;
    GEMM_CORE(A, Bt)
#pragma unroll
    for (int j = 0; j < 4; j++) {
        int gc = n0 + wc + j * 16 + lm;
        float bs = bias[gc];
#pragma unroll
        for (int i = 0; i < 4; i++) {
            int gr = m0 + wr + i * 16 + q * 4;
#pragma unroll
            for (int r = 0; r < 4; r++)
                Cmat[(size_t)(gr + r) * 384 + gc] = acc[i][j][r] + bs;
        }
    }
}

// ---------------------------------------------------------------------------
// kv_mfma: KV[g][grp][d][e] = (1/512) sum_{n in graph g} k[n][grp][d] v[n][grp][e]
// One block per (g, grp): 768 blocks x 256 threads (4 waves), 32x32xK MFMA
// over the graph's nodes.  k = rope(ones).  fp32 flat [d][e] output. VERIFIED.
__global__ __launch_bounds__(256) void kv_mfma(
    const u16* __restrict__ V, const float* __restrict__ pos,
    const int* __restrict__ batch, const float* __restrict__ freqs,
    float* __restrict__ KV) {
    const int bid = blockIdx.x;               // 768 = 64 graphs * 12 groups
    const int xcd = bid & 7, jj = bid >> 3;   // jj 0..95
    const int g = (xcd << 3) + jj / 12, grp = jj % 12;

    const int tid = threadIdx.x;
    const int w = tid >> 6, lane = tid & 63;
    const int hi = lane >> 5, de = lane & 31; // A-row d == B-col e == de
    const int p = de >> 1, sgn = de & 1;

    const float f0 = freqs[(grp * P_PAIR + p) * 3 + 0];
    const float f1 = freqs[(grp * P_PAIR + p) * 3 + 1];
    const float f2 = freqs[(grp * P_PAIR + p) * 3 + 2];

    // segment bounds (uniform across block)
    int s0 = 0, s1 = N_NODES;
    while (s0 < s1) { int m = (s0 + s1) >> 1; if (batch[m] < g) s0 = m + 1; else s1 = m; }
    const int start = s0;
    int e0 = start, e1 = N_NODES;
    while (e0 < e1) { int m = (e0 + e1) >> 1; if (batch[m] < g + 1) e0 = m + 1; else e1 = m; }
    const int end = e0;

    __shared__ __align__(1024) u16 vbuf[2048];   // 64 nodes x 32 e (bf16), 4KB
    __shared__ float posb[192];                  // 64 nodes x 3
    __shared__ __align__(16) float red[4096];    // 4 waves x 32x32 partials

    f32x16 acc;
#pragma unroll
    for (int r = 0; r < 16; r++) acc[r] = 0.0f;

    const int nl0 = w * 16 + hi * 8;             // this half-wave's first local node

    for (int c = start; c < end; c += 64) {
        __syncthreads();                         // prior chunk's readers done
        if (tid < 192) {                         // stage pos[c .. c+64)
            int i = c * 3 + tid;
            posb[tid] = (i < 3 * N_NODES) ? pos[i] : 0.0f;
        }
        {                                        // stage V slice: 64 rows x 64B
            int r = tid >> 2;
            int nn = c + r;
            const u16* gp = V + (size_t)nn * K_DIM + (grp << 5) + ((tid & 3) << 3);
            if (nn < N_NODES)
                __builtin_amdgcn_global_load_lds((gbl_void*)gp,
                                                 (lds_void*)&vbuf[w << 9], 16, 0, 0);
        }
        __syncthreads();                         // drains vmcnt (glds) too

        union { bf16x8 v; u16 u[8]; } A, B;
#pragma unroll
        for (int j = 0; j < 8; j++) {
            int nl = nl0 + j;                    // local node 0..63
            int n = c + nl;
            float ph = posb[nl * 3 + 0] * f0 + posb[nl * 3 + 1] * f1
                     + posb[nl * 3 + 2] * f2;
            float sn, cs;
            __sincosf(ph, &sn, &cs);
            float kd = sgn ? (sn + cs) : (cs - sn);
            bool valid = n < end;
            A.u[j] = valid ? f2bf(kd) : (u16)0;
            B.u[j] = valid ? vbuf[(nl << 5) + de] : (u16)0;
        }
        acc = __builtin_amdgcn_mfma_f32_32x32x16_bf16(A.v, B.v, acc, 0, 0, 0);
    }

    // reduce 4 wave-partials through LDS; C/D map: col=lane&31,
    // row=(reg&3)+8*(reg>>2)+4*(lane>>5)
#pragma unroll
    for (int r = 0; r < 16; r++) {
        int d = (r & 3) + ((r >> 2) << 3) + (hi << 2);
        red[(w << 10) + (d << 5) + de] = acc[r];
    }
    __syncthreads();
    {
        int i4 = tid << 2;
        f32x4 a0 = *reinterpret_cast<const f32x4*>(&red[i4]);
        f32x4 a1 = *reinterpret_cast<const f32x4*>(&red[1024 + i4]);
        f32x4 a2 = *reinterpret_cast<const f32x4*>(&red[2048 + i4]);
        f32x4 a3 = *reinterpret_cast<const f32x4*>(&red[3072 + i4]);
        f32x4 s = (a0 + a1 + a2 + a3) * (1.0f / 512.0f);
        *reinterpret_cast<f32x4*>(&KV[((size_t)(g * 12 + grp) << 10) + i4]) = s;
    }
}

// ---------------------------------------------------------------------------
// attn_mfma: O[n][grp*32+e] = sum_d rope(q)[n][grp][d] * KV[batch[n]][grp][d][e]
// One block per (128-node chunk, grp): 3072 blocks x 256 threads (4 waves).
// VERIFIED round-10.
__global__ __launch_bounds__(256) void attn_mfma(
    u16* __restrict__ Qw, const float* __restrict__ pos,
    const int* __restrict__ batch, const float* __restrict__ freqs,
    const float* __restrict__ KV) {
    const int bid = blockIdx.x;               // 3072 = 256 chunks * 12 groups
    const int xcd = bid & 7, jj = bid >> 3;   // jj 0..383
    const int chunk = (xcd << 5) + jj / 12, grp = jj % 12;
    const int nbase = chunk << 7;

    const int tid = threadIdx.x;
    const int w = tid >> 6, lane = tid & 63;
    const int hi = lane >> 5, de = lane & 31;

    __shared__ float sfreq[48];               // this grp: 16 pairs x 3
    __shared__ __align__(16) float red[4096]; // O tile fp32 [128][32]

    if (tid < 48) sfreq[tid] = freqs[grp * 48 + tid];

    const int node = nbase + (w << 5) + de;
    const float p0 = pos[node * 3 + 0];
    const float p1 = pos[node * 3 + 1];
    const float p2 = pos[node * 3 + 2];
    const int bnode = batch[node];
    const int g0 = batch[nbase + (w << 5)];
    const int g1 = batch[nbase + (w << 5) + 31];

    // raw Q fragment: A layout row = de (node), k = hi*8+j (d within group)
    union { bf16x8 v; u16 u[8]; } qlo, qhi, alo, ahi;
    {
        const u16* qp = Qw + (size_t)node * K_DIM + (grp << 5) + (hi << 3);
        qlo.v = *reinterpret_cast<const bf16x8*>(qp);        // d = hi*8+j
        qhi.v = *reinterpret_cast<const bf16x8*>(qp + 16);   // d = 16+hi*8+j
    }
    __syncthreads();                          // sfreq visible
#pragma unroll
    for (int z = 0; z < 4; z++) {
        const int pl = (hi << 2) + z;                        // pair for lo half
        const float* F  = &sfreq[pl * 3];
        const float* F2 = &sfreq[(8 + pl) * 3];              // pair for hi half
        float sn, cs, sn2, cs2;
        __sincosf(p0 * F[0]  + p1 * F[1]  + p2 * F[2],  &sn,  &cs);
        __sincosf(p0 * F2[0] + p1 * F2[1] + p2 * F2[2], &sn2, &cs2);
        float x1 = bf2f(qlo.u[2 * z]), x2 = bf2f(qlo.u[2 * z + 1]);
        alo.u[2 * z]     = f2bf(x1 * cs - x2 * sn);
        alo.u[2 * z + 1] = f2bf(x1 * sn + x2 * cs);
        float y1 = bf2f(qhi.u[2 * z]), y2 = bf2f(qhi.u[2 * z + 1]);
        ahi.u[2 * z]     = f2bf(y1 * cs2 - y2 * sn2);
        ahi.u[2 * z + 1] = f2bf(y1 * sn2 + y2 * cs2);
    }

    f32x16 oacc;
#pragma unroll
    for (int r = 0; r < 16; r++) oacc[r] = 0.0f;
    for (int g = g0; g <= g1; g++) {
        const bool msk = (bnode == g);
        union { bf16x8 v; u16 u[8]; } ml, mh, bl, bh;
#pragma unroll
        for (int j = 0; j < 8; j++) {
            ml.u[j] = msk ? alo.u[j] : (u16)0;
            mh.u[j] = msk ? ahi.u[j] : (u16)0;
        }
        const float* kvp = KV + (((size_t)(g * 12 + grp)) << 10) + de;
#pragma unroll
        for (int j = 0; j < 8; j++) {                        // B[k=d][col=e=de]
            bl.u[j] = f2bf(kvp[(hi * 8 + j) << 5]);
            bh.u[j] = f2bf(kvp[(16 + hi * 8 + j) << 5]);
        }
        oacc = __builtin_amdgcn_mfma_f32_32x32x16_bf16(ml.v, bl.v, oacc, 0, 0, 0);
        oacc = __builtin_amdgcn_mfma_f32_32x32x16_bf16(mh.v, bh.v, oacc, 0, 0, 0);
    }

    // C/D map: col=lane&31, row=(reg&3)+8*(reg>>2)+4*(lane>>5)
#pragma unroll
    for (int r = 0; r < 16; r++) {
        int rl = (r & 3) + ((r >> 2) << 3) + (hi << 2);
        red[((w << 5) + rl) * 32 + de] = oacc[r];
    }
    __syncthreads();
    {
        const int row = tid >> 1, half = tid & 1;
        union { u16 u[16]; float4 v[2]; } pk;
#pragma unroll
        for (int z = 0; z < 16; z++)
            pk.u[z] = f2bf(red[row * 32 + half * 16 + z]);
        float4* dst = reinterpret_cast<float4*>(
            Qw + (size_t)(nbase + row) * K_DIM + (grp << 5) + (half << 4));
        dst[0] = pk.v[0];
        dst[1] = pk.v[1];
    }
}

// ---------------------------------------------------------------------------
extern "C" void kernel_launch(void* const* d_in, const int* in_sizes, int n_in,
                              void* d_out, int out_size, void* d_ws, size_t ws_size,
                              hipStream_t stream) {
    const float* x     = (const float*)d_in[0];
    const float* pos   = (const float*)d_in[1];
    const int*   batch = (const int*)d_in[2];
    const float* Wq    = (const float*)d_in[3];
    const float* bq    = (const float*)d_in[4];
    const float* Wv    = (const float*)d_in[5];
    const float* bv    = (const float*)d_in[6];
    const float* Wo    = (const float*)d_in[7];
    const float* bo    = (const float*)d_in[8];
    const float* fr    = (const float*)d_in[9];
    float* out = (float*)d_out;

    char* ws = (char*)d_ws;                   // total use ~29.2 MB
    float* KV   = (float*)(ws);               //  3,145,728 B  [g][grp][d][e] fp32
    u16*   WqvT = (u16*)(ws + 3145728);       //    589,824 B
    u16*   WoT  = (u16*)(ws + 3735552);       //    294,912 B
    u16*   Qw   = (u16*)(ws + 4030464);       // 25,165,824 B (Q, then O in-place)
    // d_out (50.3 MB fp32) doubles as scratch until gemm_out overwrites it:
    u16*   Vd   = (u16*)d_out;                // [0, 25.2 MB): V bf16
    u16*   xb   = (u16*)d_out + N_NODES * 384;// [25.2, 50.3 MB): x as bf16

    prep<<<dim3(6576), dim3(256), 0, stream>>>(x, Wq, Wv, Wo, xb, WqvT, WoT);
    gemm_qv<<<dim3(1536), dim3(256), 0, stream>>>(xb, WqvT, bq, bv, Qw, Vd);
    kv_mfma<<<dim3(768), dim3(256), 0, stream>>>(Vd, pos, batch, fr, KV);
    attn_mfma<<<dim3(3072), dim3(256), 0, stream>>>(Qw, pos, batch, fr, KV);
    gemm_out<<<dim3(768), dim3(256), 0, stream>>>(Qw, WoT, bo, out);
}